// Round 1
// baseline (564.460 us; speedup 1.0000x reference)
//
#include <hip/hip_runtime.h>
#include <cstdint>
#include <cstddef>

#define N_NODES 50000
#define N_EDGES 1600000
#define NEG_SLOPE 0.2f
#define GAT_EPS 1e-16f

// ---------------- CSR build ----------------

__global__ void k_count(const int* __restrict__ ei, int* __restrict__ cnt) {
    int i = blockIdx.x * blockDim.x + threadIdx.x;
    if (i < N_EDGES) atomicAdd(&cnt[ei[N_EDGES + i]], 1);
}

__global__ void k_scan(const int* __restrict__ cnt, int* __restrict__ row_start) {
    __shared__ int wsum[16];
    __shared__ int chunk_base;
    int t = threadIdx.x;
    int lane = t & 63, wid = t >> 6;
    if (t == 0) chunk_base = 0;
    __syncthreads();
    for (int base = 0; base < N_NODES; base += 1024) {
        int i = base + t;
        int v = (i < N_NODES) ? cnt[i] : 0;
        int x = v;
#pragma unroll
        for (int off = 1; off < 64; off <<= 1) {
            int y = __shfl_up(x, off, 64);
            if (lane >= off) x += y;
        }
        if (lane == 63) wsum[wid] = x;
        __syncthreads();
        int woff = 0;
        for (int j = 0; j < wid; ++j) woff += wsum[j];
        int excl = chunk_base + woff + x - v;
        if (i < N_NODES) row_start[i] = excl;
        __syncthreads();
        if (t == 1023) chunk_base = excl + v;
        __syncthreads();
    }
    if (t == 0) row_start[N_NODES] = chunk_base;
}

__global__ void k_scatter(const int* __restrict__ ei, const int* __restrict__ row_start,
                          int* __restrict__ fill, int* __restrict__ csr_src) {
    int i = blockIdx.x * blockDim.x + threadIdx.x;
    if (i < N_EDGES) {
        int d = ei[N_EDGES + i];
        int pos = atomicAdd(&fill[d], 1);
        csr_src[row_start[d] + pos] = ei[i];
    }
}

// ---------------- Layer 1 GEMM: h1 = x @ W1, + attention scalars ----------------
// 32 nodes/block, W1 (128x128, 64KB) in LDS, each thread: 1 channel x 16 nodes.

__global__ __launch_bounds__(256) void k_gemm1(
    const float* __restrict__ x, const float* __restrict__ W1,
    const float* __restrict__ att_src, const float* __restrict__ att_dst,
    float* __restrict__ h1, float* __restrict__ a_src, float* __restrict__ a_dst) {
    __shared__ float wl[128 * 128];
    __shared__ float xl[32 * 128];
    int t = threadIdx.x;
    int node0 = blockIdx.x * 32;
    {
        const float4* Wv = (const float4*)W1;
        float4* wlv = (float4*)wl;
        for (int j = t; j < 128 * 128 / 4; j += 256) wlv[j] = Wv[j];
    }
    {
        float4* xlv = (float4*)xl;
        for (int j = t; j < 32 * 128 / 4; j += 256) {
            int n = j >> 5;
            int rem = j & 31;
            int gn = node0 + n;
            float4 v = make_float4(0.f, 0.f, 0.f, 0.f);
            if (gn < N_NODES) v = ((const float4*)x)[(size_t)gn * 32 + rem];
            xlv[j] = v;
        }
    }
    __syncthreads();
    int c = t & 127;   // output channel (head = c/64)
    int nb = t >> 7;   // node sub-tile: nodes nb*16 .. nb*16+15
    float acc[16];
#pragma unroll
    for (int n = 0; n < 16; ++n) acc[n] = 0.f;
    for (int k4 = 0; k4 < 32; ++k4) {
        int k = k4 * 4;
        float w0 = wl[(k + 0) * 128 + c];
        float w1_ = wl[(k + 1) * 128 + c];
        float w2_ = wl[(k + 2) * 128 + c];
        float w3_ = wl[(k + 3) * 128 + c];
#pragma unroll
        for (int n = 0; n < 16; ++n) {
            float4 xv = ((const float4*)(xl + (nb * 16 + n) * 128))[k4];
            acc[n] += w0 * xv.x + w1_ * xv.y + w2_ * xv.z + w3_ * xv.w;
        }
    }
    float as_c = att_src[c];
    float ad_c = att_dst[c];
    int lane = t & 63;
    int head = (c >= 64) ? 1 : 0;
#pragma unroll
    for (int n = 0; n < 16; ++n) {
        int gn = node0 + nb * 16 + n;
        float hv = acc[n];
        float ps = hv * as_c;
        float pd = hv * ad_c;
#pragma unroll
        for (int off = 32; off >= 1; off >>= 1) {
            ps += __shfl_xor(ps, off, 64);
            pd += __shfl_xor(pd, off, 64);
        }
        if (gn < N_NODES) {
            h1[(size_t)gn * 128 + c] = hv;
            if (lane == 0) {
                a_src[gn * 2 + head] = ps;
                a_dst[gn * 2 + head] = pd;
            }
        }
    }
}

// ---------------- Layer 1 aggregation: one wave per destination node ----------------

__global__ __launch_bounds__(256) void k_agg1(
    const int* __restrict__ row_start, const int* __restrict__ csr_src,
    const float* __restrict__ h1, const float* __restrict__ a_src,
    const float* __restrict__ a_dst, const float* __restrict__ b1,
    float* __restrict__ out1) {
    int wid = (blockIdx.x * blockDim.x + threadIdx.x) >> 6;
    int lane = threadIdx.x & 63;
    if (wid >= N_NODES) return;
    int d = wid;
    int row = row_start[d], end = row_start[d + 1];
    float2 ad = ((const float2*)a_dst)[d];
    // pass 1: softmax denominator per head (no max-shift: |e| <= ~8, exact math)
    float den0 = 0.f, den1 = 0.f;
    for (int i = row + lane; i < end; i += 64) {
        int s = csr_src[i];
        float2 as = ((const float2*)a_src)[s];
        float e0 = as.x + ad.x; e0 = (e0 >= 0.f) ? e0 : NEG_SLOPE * e0;
        float e1 = as.y + ad.y; e1 = (e1 >= 0.f) ? e1 : NEG_SLOPE * e1;
        den0 += expf(e0);
        den1 += expf(e1);
    }
#pragma unroll
    for (int off = 32; off >= 1; off >>= 1) {
        den0 += __shfl_xor(den0, off, 64);
        den1 += __shfl_xor(den1, off, 64);
    }
    float inv0 = 1.f / (den0 + GAT_EPS), inv1 = 1.f / (den1 + GAT_EPS);
    int head = lane >> 5;            // lane covers channels 2*lane, 2*lane+1
    float inv = head ? inv1 : inv0;
    float adh = head ? ad.y : ad.x;
    float accx = 0.f, accy = 0.f;
    int i = row;
    for (; i + 2 <= end; i += 2) {
        int s0 = csr_src[i], s1 = csr_src[i + 1];
        float2 as0 = ((const float2*)a_src)[s0];
        float2 as1 = ((const float2*)a_src)[s1];
        float2 h0 = ((const float2*)(h1 + (size_t)s0 * 128))[lane];
        float2 hv1 = ((const float2*)(h1 + (size_t)s1 * 128))[lane];
        float e0 = (head ? as0.y : as0.x) + adh; e0 = (e0 >= 0.f) ? e0 : NEG_SLOPE * e0;
        float e1 = (head ? as1.y : as1.x) + adh; e1 = (e1 >= 0.f) ? e1 : NEG_SLOPE * e1;
        float w0 = expf(e0) * inv, w1 = expf(e1) * inv;
        accx += w0 * h0.x + w1 * hv1.x;
        accy += w0 * h0.y + w1 * hv1.y;
    }
    for (; i < end; ++i) {
        int s = csr_src[i];
        float2 as = ((const float2*)a_src)[s];
        float2 hv = ((const float2*)(h1 + (size_t)s * 128))[lane];
        float e = (head ? as.y : as.x) + adh; e = (e >= 0.f) ? e : NEG_SLOPE * e;
        float w = expf(e) * inv;
        accx += w * hv.x; accy += w * hv.y;
    }
    int c0 = lane * 2;
    float ox = accx + b1[c0], oy = accy + b1[c0 + 1];
    // ELU (alpha=1)
    ox = (ox > 0.f) ? ox : expm1f(ox);
    oy = (oy > 0.f) ? oy : expm1f(oy);
    ((float2*)(out1 + (size_t)d * 128))[lane] = make_float2(ox, oy);
}

// ---------------- Layer 2 GEMM: h2 = elu_out @ W2, + attention scalars ----------------

__global__ __launch_bounds__(256) void k_gemm2(
    const float* __restrict__ out1, const float* __restrict__ W2,
    const float* __restrict__ att_src2, const float* __restrict__ att_dst2,
    float* __restrict__ h2, float* __restrict__ a_src2, float* __restrict__ a_dst2) {
    __shared__ float wl[128 * 16];
    __shared__ float xl[16 * 128];
    int t = threadIdx.x;
    int node0 = blockIdx.x * 16;
    for (int j = t; j < 128 * 16 / 4; j += 256) ((float4*)wl)[j] = ((const float4*)W2)[j];
    for (int j = t; j < 16 * 128 / 4; j += 256) {
        int n = j >> 5;
        int rem = j & 31;
        int gn = node0 + n;
        float4 v = make_float4(0.f, 0.f, 0.f, 0.f);
        if (gn < N_NODES) v = ((const float4*)out1)[(size_t)gn * 32 + rem];
        ((float4*)xl)[j] = v;
    }
    __syncthreads();
    int c = t & 15;
    int ln = t >> 4;
    float acc = 0.f;
    for (int k4 = 0; k4 < 32; ++k4) {
        float4 xv = ((const float4*)(xl + ln * 128))[k4];
        int k = k4 * 4;
        acc += xv.x * wl[(k + 0) * 16 + c] + xv.y * wl[(k + 1) * 16 + c] +
               xv.z * wl[(k + 2) * 16 + c] + xv.w * wl[(k + 3) * 16 + c];
    }
    float ps = acc * att_src2[c];
    float pd = acc * att_dst2[c];
#pragma unroll
    for (int off = 8; off >= 1; off >>= 1) {
        ps += __shfl_xor(ps, off, 16);
        pd += __shfl_xor(pd, off, 16);
    }
    int gn = node0 + ln;
    if (gn < N_NODES) {
        h2[(size_t)gn * 16 + c] = acc;
        if (c == 0) { a_src2[gn] = ps; a_dst2[gn] = pd; }
    }
}

// ---------------- Layer 2 aggregation + bias + softmax: 16 lanes per node ----------------

__global__ __launch_bounds__(256) void k_agg2(
    const int* __restrict__ row_start, const int* __restrict__ csr_src,
    const float* __restrict__ h2, const float* __restrict__ a_src2,
    const float* __restrict__ a_dst2, const float* __restrict__ b2,
    float* __restrict__ out) {
    int gid = blockIdx.x * blockDim.x + threadIdx.x;
    int d = gid >> 4;
    int c = gid & 15;
    if (d >= N_NODES) return;
    int row = row_start[d], end = row_start[d + 1];
    float ad = a_dst2[d];
    float den = 0.f;
    for (int i = row + c; i < end; i += 16) {
        float e = a_src2[csr_src[i]] + ad;
        e = (e >= 0.f) ? e : NEG_SLOPE * e;
        den += expf(e);
    }
#pragma unroll
    for (int off = 8; off >= 1; off >>= 1) den += __shfl_xor(den, off, 16);
    float inv = 1.f / (den + GAT_EPS);
    float acc = 0.f;
    int i = row;
    for (; i + 2 <= end; i += 2) {
        int s0 = csr_src[i], s1 = csr_src[i + 1];
        float e0 = a_src2[s0] + ad; e0 = (e0 >= 0.f) ? e0 : NEG_SLOPE * e0;
        float e1 = a_src2[s1] + ad; e1 = (e1 >= 0.f) ? e1 : NEG_SLOPE * e1;
        float w0 = expf(e0) * inv, w1 = expf(e1) * inv;
        acc += w0 * h2[(size_t)s0 * 16 + c] + w1 * h2[(size_t)s1 * 16 + c];
    }
    for (; i < end; ++i) {
        int s = csr_src[i];
        float e = a_src2[s] + ad; e = (e >= 0.f) ? e : NEG_SLOPE * e;
        acc += expf(e) * inv * h2[(size_t)s * 16 + c];
    }
    float v = acc + b2[c];
    // softmax over the 16 channels
    float m = v;
#pragma unroll
    for (int off = 8; off >= 1; off >>= 1) m = fmaxf(m, __shfl_xor(m, off, 16));
    float ex = expf(v - m);
    float sum = ex;
#pragma unroll
    for (int off = 8; off >= 1; off >>= 1) sum += __shfl_xor(sum, off, 16);
    out[(size_t)d * 16 + c] = ex / sum;
}

// ---------------- launch ----------------

extern "C" void kernel_launch(void* const* d_in, const int* in_sizes, int n_in,
                              void* d_out, int out_size, void* d_ws, size_t ws_size,
                              hipStream_t stream) {
    const float* x        = (const float*)d_in[0];
    const float* W1       = (const float*)d_in[1];
    const float* att_src1 = (const float*)d_in[2];
    const float* att_dst1 = (const float*)d_in[3];
    const float* b1       = (const float*)d_in[4];
    const float* W2       = (const float*)d_in[5];
    const float* att_src2 = (const float*)d_in[6];
    const float* att_dst2 = (const float*)d_in[7];
    const float* b2       = (const float*)d_in[8];
    const int*   ei       = (const int*)d_in[9];   // [2, E]: src row then dst row

    char* p = (char*)d_ws;
    auto alloc = [&](size_t bytes) {
        char* r = p;
        p += (bytes + 255) & ~(size_t)255;
        return r;
    };
    float* h1      = (float*)alloc(sizeof(float) * (size_t)N_NODES * 128);
    float* out1    = (float*)alloc(sizeof(float) * (size_t)N_NODES * 128);
    float* h2      = (float*)alloc(sizeof(float) * (size_t)N_NODES * 16);
    float* a_src   = (float*)alloc(sizeof(float) * N_NODES * 2);
    float* a_dst   = (float*)alloc(sizeof(float) * N_NODES * 2);
    float* as2     = (float*)alloc(sizeof(float) * N_NODES);
    float* ad2     = (float*)alloc(sizeof(float) * N_NODES);
    int* cnt       = (int*)alloc(sizeof(int) * N_NODES * 2);  // cnt + fill, adjacent
    int* fill      = cnt + N_NODES;
    int* row_start = (int*)alloc(sizeof(int) * (N_NODES + 1));
    int* csr_src   = (int*)alloc(sizeof(int) * N_EDGES);

    hipMemsetAsync(cnt, 0, sizeof(int) * N_NODES * 2, stream);
    k_count<<<(N_EDGES + 255) / 256, 256, 0, stream>>>(ei, cnt);
    k_scan<<<1, 1024, 0, stream>>>(cnt, row_start);
    k_scatter<<<(N_EDGES + 255) / 256, 256, 0, stream>>>(ei, row_start, fill, csr_src);
    k_gemm1<<<(N_NODES + 31) / 32, 256, 0, stream>>>(x, W1, att_src1, att_dst1, h1, a_src, a_dst);
    k_agg1<<<(N_NODES * 64 + 255) / 256, 256, 0, stream>>>(row_start, csr_src, h1, a_src, a_dst, b1, out1);
    k_gemm2<<<(N_NODES + 15) / 16, 256, 0, stream>>>(out1, W2, att_src2, att_dst2, h2, as2, ad2);
    k_agg2<<<(N_NODES * 16 + 255) / 256, 256, 0, stream>>>(row_start, csr_src, h2, as2, ad2, b2, (float*)d_out);
}

// Round 3
// 548.866 us; speedup vs baseline: 1.0284x; 1.0284x over previous
//
#include <hip/hip_runtime.h>
#include <cstdint>
#include <cstddef>

#define N_NODES 50000
#define N_EDGES 1600000
#define NEG_SLOPE 0.2f
#define GAT_EPS 1e-16f

// ---------------- CSR build ----------------

__global__ void k_count(const int* __restrict__ ei, int* __restrict__ cnt) {
    int i = blockIdx.x * blockDim.x + threadIdx.x;
    if (i < N_EDGES) atomicAdd(&cnt[ei[N_EDGES + i]], 1);
}

__global__ void k_scan(const int* __restrict__ cnt, int* __restrict__ row_start) {
    __shared__ int wsum[16];
    __shared__ int chunk_base;
    int t = threadIdx.x;
    int lane = t & 63, wid = t >> 6;
    if (t == 0) chunk_base = 0;
    __syncthreads();
    for (int base = 0; base < N_NODES; base += 1024) {
        int i = base + t;
        int v = (i < N_NODES) ? cnt[i] : 0;
        int x = v;
#pragma unroll
        for (int off = 1; off < 64; off <<= 1) {
            int y = __shfl_up(x, off, 64);
            if (lane >= off) x += y;
        }
        if (lane == 63) wsum[wid] = x;
        __syncthreads();
        int woff = 0;
        for (int j = 0; j < wid; ++j) woff += wsum[j];
        int excl = chunk_base + woff + x - v;
        if (i < N_NODES) row_start[i] = excl;
        __syncthreads();
        if (t == 1023) chunk_base = excl + v;
        __syncthreads();
    }
    if (t == 0) row_start[N_NODES] = chunk_base;
}

// scatter + fused layer-1 edge weight computation (runs after gemm1)
__global__ void k_scatter_w(const int* __restrict__ ei, const int* __restrict__ row_start,
                            int* __restrict__ fill, int* __restrict__ csr_src,
                            int* __restrict__ csr_dst,
                            const float* __restrict__ a_src1, const float* __restrict__ a_dst1,
                            float* __restrict__ w1_csr) {
    int i = blockIdx.x * blockDim.x + threadIdx.x;
    if (i >= N_EDGES) return;
    int s = ei[i];
    int d = ei[N_EDGES + i];
    int pos = atomicAdd(&fill[d], 1);
    int slot = row_start[d] + pos;
    csr_src[slot] = s;
    csr_dst[slot] = d;
    float2 as = ((const float2*)a_src1)[s];
    float2 ad = ((const float2*)a_dst1)[d];
    float e0 = as.x + ad.x; e0 = (e0 >= 0.f) ? e0 : NEG_SLOPE * e0;
    float e1 = as.y + ad.y; e1 = (e1 >= 0.f) ? e1 : NEG_SLOPE * e1;
    ((float2*)w1_csr)[slot] = make_float2(expf(e0), expf(e1));
}

// ---------------- Layer 1 GEMM: h1 = x @ W1, + attention scalars ----------------

__global__ __launch_bounds__(256) void k_gemm1(
    const float* __restrict__ x, const float* __restrict__ W1,
    const float* __restrict__ att_src, const float* __restrict__ att_dst,
    float* __restrict__ h1, float* __restrict__ a_src, float* __restrict__ a_dst) {
    __shared__ float wl[128 * 128];
    __shared__ float xl[32 * 128];
    int t = threadIdx.x;
    int node0 = blockIdx.x * 32;
    {
        const float4* Wv = (const float4*)W1;
        float4* wlv = (float4*)wl;
        for (int j = t; j < 128 * 128 / 4; j += 256) wlv[j] = Wv[j];
    }
    {
        float4* xlv = (float4*)xl;
        for (int j = t; j < 32 * 128 / 4; j += 256) {
            int n = j >> 5;
            int rem = j & 31;
            int gn = node0 + n;
            float4 v = make_float4(0.f, 0.f, 0.f, 0.f);
            if (gn < N_NODES) v = ((const float4*)x)[(size_t)gn * 32 + rem];
            xlv[j] = v;
        }
    }
    __syncthreads();
    int c = t & 127;   // output channel (head = c/64)
    int nb = t >> 7;   // node sub-tile: nodes nb*16 .. nb*16+15
    float acc[16];
#pragma unroll
    for (int n = 0; n < 16; ++n) acc[n] = 0.f;
    for (int k4 = 0; k4 < 32; ++k4) {
        int k = k4 * 4;
        float w0 = wl[(k + 0) * 128 + c];
        float w1_ = wl[(k + 1) * 128 + c];
        float w2_ = wl[(k + 2) * 128 + c];
        float w3_ = wl[(k + 3) * 128 + c];
#pragma unroll
        for (int n = 0; n < 16; ++n) {
            float4 xv = ((const float4*)(xl + (nb * 16 + n) * 128))[k4];
            acc[n] += w0 * xv.x + w1_ * xv.y + w2_ * xv.z + w3_ * xv.w;
        }
    }
    float as_c = att_src[c];
    float ad_c = att_dst[c];
    int lane = t & 63;
    int head = (c >= 64) ? 1 : 0;
#pragma unroll
    for (int n = 0; n < 16; ++n) {
        int gn = node0 + nb * 16 + n;
        float hv = acc[n];
        float ps = hv * as_c;
        float pd = hv * ad_c;
#pragma unroll
        for (int off = 32; off >= 1; off >>= 1) {
            ps += __shfl_xor(ps, off, 64);
            pd += __shfl_xor(pd, off, 64);
        }
        if (gn < N_NODES) {
            h1[(size_t)gn * 128 + c] = hv;
            if (lane == 0) {
                a_src[gn * 2 + head] = ps;
                a_dst[gn * 2 + head] = pd;
            }
        }
    }
}

// ---------------- Layer 1 aggregation + ELU + fused layer-2 GEMM ----------------
// One wave per destination node; lane owns channels 2*lane, 2*lane+1.
// Grid: 50000 nodes / 4 waves per block = 12500 blocks exactly (no inactive waves).

__global__ __launch_bounds__(256) void k_agg1f(
    const int* __restrict__ row_start, const int* __restrict__ csr_src,
    const float* __restrict__ h1, const float* __restrict__ w1_csr,
    const float* __restrict__ b1, const float* __restrict__ W2,
    const float* __restrict__ att_src2, const float* __restrict__ att_dst2,
    float* __restrict__ h2, float* __restrict__ as2, float* __restrict__ ad2) {
    __shared__ float w2t[16 * 132];     // W2 transposed, row padded to 132 (16B-aligned)
    __shared__ float rows[4][128];      // post-ELU layer-1 output row per wave
    int t = threadIdx.x;
    // stage W2^T: W2 is [128][16]
    for (int i = t; i < 2048; i += 256) {
        int k = i >> 4, j = i & 15;
        w2t[j * 132 + k] = W2[i];
    }
    int wv = t >> 6, lane = t & 63;
    int d = blockIdx.x * 4 + wv;
    int row = row_start[d], end = row_start[d + 1];
    const float2* w1v = (const float2*)w1_csr;
    // pass 1: per-head denominators (coalesced strided read of w1)
    float den0 = 0.f, den1 = 0.f;
    for (int i = row + lane; i < end; i += 64) {
        float2 w = w1v[i];
        den0 += w.x; den1 += w.y;
    }
#pragma unroll
    for (int off = 32; off >= 1; off >>= 1) {
        den0 += __shfl_xor(den0, off, 64);
        den1 += __shfl_xor(den1, off, 64);
    }
    int head = lane >> 5;
    float inv = 1.f / ((head ? den1 : den0) + GAT_EPS);
    // pass 2: weighted gather-accumulate (weights broadcast, h1 coalesced)
    float accx = 0.f, accy = 0.f;
    int i = row;
    for (; i + 2 <= end; i += 2) {
        int s0 = csr_src[i], s1 = csr_src[i + 1];
        float2 w0 = w1v[i], w1e = w1v[i + 1];
        float2 ha = ((const float2*)(h1 + (size_t)s0 * 128))[lane];
        float2 hb = ((const float2*)(h1 + (size_t)s1 * 128))[lane];
        float wa = head ? w0.y : w0.x;
        float wb = head ? w1e.y : w1e.x;
        accx += wa * ha.x + wb * hb.x;
        accy += wa * ha.y + wb * hb.y;
    }
    if (i < end) {
        int s = csr_src[i];
        float2 w0 = w1v[i];
        float2 ha = ((const float2*)(h1 + (size_t)s * 128))[lane];
        float wa = head ? w0.y : w0.x;
        accx += wa * ha.x; accy += wa * ha.y;
    }
    accx *= inv; accy *= inv;
    int c0 = lane * 2;
    float ox = accx + b1[c0], oy = accy + b1[c0 + 1];
    ox = (ox > 0.f) ? ox : expm1f(ox);   // ELU
    oy = (oy > 0.f) ? oy : expm1f(oy);
    rows[wv][c0] = ox;
    rows[wv][c0 + 1] = oy;
    __syncthreads();
    // fused gemm2: lane = j + 16*q; output j, k-range q*32..q*32+31
    int j = lane & 15, q = lane >> 4;
    const float* r = rows[wv];
    const float* wt = &w2t[j * 132];
    int k0 = q * 32;
    float acc2 = 0.f;
#pragma unroll
    for (int kk = 0; kk < 32; kk += 4) {
        float4 rv = *(const float4*)(r + k0 + kk);
        float4 w4 = *(const float4*)(wt + k0 + kk);
        acc2 += rv.x * w4.x + rv.y * w4.y + rv.z * w4.z + rv.w * w4.w;
    }
    acc2 += __shfl_xor(acc2, 16, 64);
    acc2 += __shfl_xor(acc2, 32, 64);
    if (lane < 16) {
        h2[(size_t)d * 16 + j] = acc2;
        float ps = acc2 * att_src2[j];
        float pd = acc2 * att_dst2[j];
#pragma unroll
        for (int off = 8; off >= 1; off >>= 1) {
            ps += __shfl_xor(ps, off, 64);
            pd += __shfl_xor(pd, off, 64);
        }
        if (lane == 0) { as2[d] = ps; ad2[d] = pd; }
    }
}

// ---------------- Layer 2 edge weights ----------------

__global__ void k_w2(const int* __restrict__ csr_src, const int* __restrict__ csr_dst,
                     const float* __restrict__ as2, const float* __restrict__ ad2,
                     float* __restrict__ w2_csr) {
    int i = blockIdx.x * blockDim.x + threadIdx.x;
    if (i >= N_EDGES) return;
    float e = as2[csr_src[i]] + ad2[csr_dst[i]];
    e = (e >= 0.f) ? e : NEG_SLOPE * e;
    w2_csr[i] = expf(e);
}

// ---------------- Layer 2 aggregation + bias + softmax: 16 lanes per node ----------------

__global__ __launch_bounds__(256) void k_agg2(
    const int* __restrict__ row_start, const int* __restrict__ csr_src,
    const float* __restrict__ h2, const float* __restrict__ w2_csr,
    const float* __restrict__ b2, float* __restrict__ out) {
    int gid = blockIdx.x * blockDim.x + threadIdx.x;
    int d = gid >> 4;
    int c = gid & 15;
    if (d >= N_NODES) return;
    int row = row_start[d], end = row_start[d + 1];
    float den = 0.f;
    for (int i = row + c; i < end; i += 16) den += w2_csr[i];
#pragma unroll
    for (int off = 8; off >= 1; off >>= 1) den += __shfl_xor(den, off, 16);
    float inv = 1.f / (den + GAT_EPS);
    float acc = 0.f;
    int i = row;
    for (; i + 2 <= end; i += 2) {
        int s0 = csr_src[i], s1 = csr_src[i + 1];
        float wa = w2_csr[i], wb = w2_csr[i + 1];
        acc += wa * h2[(size_t)s0 * 16 + c] + wb * h2[(size_t)s1 * 16 + c];
    }
    if (i < end) {
        int s = csr_src[i];
        acc += w2_csr[i] * h2[(size_t)s * 16 + c];
    }
    float v = acc * inv + b2[c];
    // softmax over the 16 channels
    float m = v;
#pragma unroll
    for (int off = 8; off >= 1; off >>= 1) m = fmaxf(m, __shfl_xor(m, off, 16));
    float ex = expf(v - m);
    float sum = ex;
#pragma unroll
    for (int off = 8; off >= 1; off >>= 1) sum += __shfl_xor(sum, off, 16);
    out[(size_t)d * 16 + c] = ex / sum;
}

// ---------------- launch ----------------

extern "C" void kernel_launch(void* const* d_in, const int* in_sizes, int n_in,
                              void* d_out, int out_size, void* d_ws, size_t ws_size,
                              hipStream_t stream) {
    const float* x        = (const float*)d_in[0];
    const float* W1       = (const float*)d_in[1];
    const float* att_src1 = (const float*)d_in[2];
    const float* att_dst1 = (const float*)d_in[3];
    const float* b1       = (const float*)d_in[4];
    const float* W2       = (const float*)d_in[5];
    const float* att_src2 = (const float*)d_in[6];
    const float* att_dst2 = (const float*)d_in[7];
    const float* b2       = (const float*)d_in[8];
    const int*   ei       = (const int*)d_in[9];   // [2, E]: src row then dst row

    char* p = (char*)d_ws;
    auto alloc = [&](size_t bytes) {
        char* r = p;
        p += (bytes + 255) & ~(size_t)255;
        return r;
    };
    float* h1      = (float*)alloc(sizeof(float) * (size_t)N_NODES * 128);
    float* h2      = (float*)alloc(sizeof(float) * (size_t)N_NODES * 16);
    float* a_src   = (float*)alloc(sizeof(float) * N_NODES * 2);
    float* a_dst   = (float*)alloc(sizeof(float) * N_NODES * 2);
    float* as2     = (float*)alloc(sizeof(float) * N_NODES);
    float* ad2     = (float*)alloc(sizeof(float) * N_NODES);
    int* cnt       = (int*)alloc(sizeof(int) * N_NODES * 2);  // cnt + fill, adjacent
    int* fill      = cnt + N_NODES;
    int* row_start = (int*)alloc(sizeof(int) * (N_NODES + 1));
    int* csr_src   = (int*)alloc(sizeof(int) * N_EDGES);
    int* csr_dst   = (int*)alloc(sizeof(int) * N_EDGES);
    float* w1_csr  = (float*)alloc(sizeof(float) * (size_t)N_EDGES * 2);
    float* w2_csr  = (float*)alloc(sizeof(float) * N_EDGES);

    (void)hipMemsetAsync(cnt, 0, sizeof(int) * N_NODES * 2, stream);
    k_count<<<(N_EDGES + 255) / 256, 256, 0, stream>>>(ei, cnt);
    k_scan<<<1, 1024, 0, stream>>>(cnt, row_start);
    k_gemm1<<<(N_NODES + 31) / 32, 256, 0, stream>>>(x, W1, att_src1, att_dst1, h1, a_src, a_dst);
    k_scatter_w<<<(N_EDGES + 255) / 256, 256, 0, stream>>>(ei, row_start, fill, csr_src, csr_dst, a_src, a_dst, w1_csr);
    k_agg1f<<<N_NODES / 4, 256, 0, stream>>>(row_start, csr_src, h1, w1_csr, b1, W2, att_src2, att_dst2, h2, as2, ad2);
    k_w2<<<(N_EDGES + 255) / 256, 256, 0, stream>>>(csr_src, csr_dst, as2, ad2, w2_csr);
    k_agg2<<<(N_NODES * 16) / 256, 256, 0, stream>>>(row_start, csr_src, h2, w2_csr, b2, (float*)d_out);
}

// Round 4
// 502.659 us; speedup vs baseline: 1.1229x; 1.0919x over previous
//
#include <hip/hip_runtime.h>
#include <hip/hip_fp16.h>
#include <cstdint>
#include <cstddef>

#define N_NODES 50000
#define N_EDGES 1600000
#define NEG_SLOPE 0.2f
#define GAT_EPS 1e-16f

// ---------------- CSR build ----------------

__global__ void k_count(const int* __restrict__ ei, int* __restrict__ cnt) {
    int i = blockIdx.x * blockDim.x + threadIdx.x;
    if (i < N_EDGES) atomicAdd(&cnt[ei[N_EDGES + i]], 1);
}

// single-block exclusive scan, 4 elems/thread (13 iterations over 50000)
__global__ void k_scan(const int* __restrict__ cnt, int* __restrict__ row_start) {
    __shared__ int wsum[16];
    __shared__ int wpre[16];
    __shared__ int total;
    __shared__ int chunk_base;
    int t = threadIdx.x;
    int lane = t & 63, wid = t >> 6;
    if (t == 0) chunk_base = 0;
    __syncthreads();
    for (int base = 0; base < N_NODES; base += 4096) {
        int i0 = base + t * 4;
        int v0 = (i0 + 0 < N_NODES) ? cnt[i0 + 0] : 0;
        int v1 = (i0 + 1 < N_NODES) ? cnt[i0 + 1] : 0;
        int v2 = (i0 + 2 < N_NODES) ? cnt[i0 + 2] : 0;
        int v3 = (i0 + 3 < N_NODES) ? cnt[i0 + 3] : 0;
        int s0 = v0, s1 = s0 + v1, s2 = s1 + v2, s3 = s2 + v3;
        int x = s3;
#pragma unroll
        for (int off = 1; off < 64; off <<= 1) {
            int y = __shfl_up(x, off, 64);
            if (lane >= off) x += y;
        }
        if (lane == 63) wsum[wid] = x;
        __syncthreads();
        if (t < 16) {
            int w = wsum[t];
            int xx = w;
#pragma unroll
            for (int off = 1; off < 16; off <<= 1) {
                int y = __shfl_up(xx, off, 16);
                if (t >= off) xx += y;
            }
            wpre[t] = xx - w;           // exclusive prefix of wave sums
            if (t == 15) total = xx;    // block total this chunk
        }
        __syncthreads();
        int excl = chunk_base + wpre[wid] + (x - s3);
        if (i0 + 3 < N_NODES) {
            ((int4*)row_start)[i0 >> 2] = make_int4(excl, excl + s0, excl + s1, excl + s2);
        } else {
            if (i0 + 0 < N_NODES) row_start[i0 + 0] = excl;
            if (i0 + 1 < N_NODES) row_start[i0 + 1] = excl + s0;
            if (i0 + 2 < N_NODES) row_start[i0 + 2] = excl + s1;
        }
        __syncthreads();
        if (t == 0) chunk_base += total;
        __syncthreads();
    }
    if (t == 0) row_start[N_NODES] = chunk_base;
}

// scatter + fused layer-1 edge weight computation (runs after gemm1)
__global__ void k_scatter_w(const int* __restrict__ ei, const int* __restrict__ row_start,
                            int* __restrict__ fill, int* __restrict__ csr_src,
                            const float* __restrict__ a_src1, const float* __restrict__ a_dst1,
                            float* __restrict__ w1_csr) {
    int i = blockIdx.x * blockDim.x + threadIdx.x;
    if (i >= N_EDGES) return;
    int s = ei[i];
    int d = ei[N_EDGES + i];
    int pos = atomicAdd(&fill[d], 1);
    int slot = row_start[d] + pos;
    csr_src[slot] = s;
    float2 as = ((const float2*)a_src1)[s];
    float2 ad = ((const float2*)a_dst1)[d];
    float e0 = as.x + ad.x; e0 = (e0 >= 0.f) ? e0 : NEG_SLOPE * e0;
    float e1 = as.y + ad.y; e1 = (e1 >= 0.f) ? e1 : NEG_SLOPE * e1;
    ((float2*)w1_csr)[slot] = make_float2(expf(e0), expf(e1));
}

// ---------------- Layer 1 GEMM: h1 = x @ W1 (fp16 out), + attention scalars ----------------

__global__ __launch_bounds__(256) void k_gemm1(
    const float* __restrict__ x, const float* __restrict__ W1,
    const float* __restrict__ att_src, const float* __restrict__ att_dst,
    __half* __restrict__ h1, float* __restrict__ a_src, float* __restrict__ a_dst) {
    __shared__ float wl[128 * 128];
    __shared__ float xl[32 * 128];
    int t = threadIdx.x;
    int node0 = blockIdx.x * 32;
    {
        const float4* Wv = (const float4*)W1;
        float4* wlv = (float4*)wl;
        for (int j = t; j < 128 * 128 / 4; j += 256) wlv[j] = Wv[j];
    }
    {
        float4* xlv = (float4*)xl;
        for (int j = t; j < 32 * 128 / 4; j += 256) {
            int n = j >> 5;
            int rem = j & 31;
            int gn = node0 + n;
            float4 v = make_float4(0.f, 0.f, 0.f, 0.f);
            if (gn < N_NODES) v = ((const float4*)x)[(size_t)gn * 32 + rem];
            xlv[j] = v;
        }
    }
    __syncthreads();
    int c = t & 127;   // output channel (head = c/64)
    int nb = t >> 7;   // node sub-tile: nodes nb*16 .. nb*16+15
    float acc[16];
#pragma unroll
    for (int n = 0; n < 16; ++n) acc[n] = 0.f;
    for (int k4 = 0; k4 < 32; ++k4) {
        int k = k4 * 4;
        float w0 = wl[(k + 0) * 128 + c];
        float w1_ = wl[(k + 1) * 128 + c];
        float w2_ = wl[(k + 2) * 128 + c];
        float w3_ = wl[(k + 3) * 128 + c];
#pragma unroll
        for (int n = 0; n < 16; ++n) {
            float4 xv = ((const float4*)(xl + (nb * 16 + n) * 128))[k4];
            acc[n] += w0 * xv.x + w1_ * xv.y + w2_ * xv.z + w3_ * xv.w;
        }
    }
    float as_c = att_src[c];
    float ad_c = att_dst[c];
    int lane = t & 63;
    int head = (c >= 64) ? 1 : 0;
#pragma unroll
    for (int n = 0; n < 16; ++n) {
        int gn = node0 + nb * 16 + n;
        float hv = acc[n];
        float ps = hv * as_c;
        float pd = hv * ad_c;
#pragma unroll
        for (int off = 32; off >= 1; off >>= 1) {
            ps += __shfl_xor(ps, off, 64);
            pd += __shfl_xor(pd, off, 64);
        }
        if (gn < N_NODES) {
            h1[(size_t)gn * 128 + c] = __float2half(hv);
            if (lane == 0) {
                a_src[gn * 2 + head] = ps;
                a_dst[gn * 2 + head] = pd;
            }
        }
    }
}

// ---------------- Layer 1 aggregation + ELU + fused layer-2 GEMM ----------------
// One wave per destination node; lane owns channels 2*lane, 2*lane+1 (one __half2).

__global__ __launch_bounds__(256) void k_agg1f(
    const int* __restrict__ row_start, const int* __restrict__ csr_src,
    const __half* __restrict__ h1, const float* __restrict__ w1_csr,
    const float* __restrict__ b1, const float* __restrict__ W2,
    const float* __restrict__ att_src2, const float* __restrict__ att_dst2,
    float* __restrict__ h2, float* __restrict__ as2, float* __restrict__ ad2) {
    __shared__ float w2t[16 * 132];     // W2 transposed, row padded to 132
    __shared__ float rows[4][128];      // post-ELU layer-1 output row per wave
    int t = threadIdx.x;
    for (int i = t; i < 2048; i += 256) {
        int k = i >> 4, j = i & 15;
        w2t[j * 132 + k] = W2[i];
    }
    int wv = t >> 6, lane = t & 63;
    int d = blockIdx.x * 4 + wv;
    int row = row_start[d], end = row_start[d + 1];
    const float2* w1v = (const float2*)w1_csr;
    // pass 1: per-head denominators
    float den0 = 0.f, den1 = 0.f;
    for (int i = row + lane; i < end; i += 64) {
        float2 w = w1v[i];
        den0 += w.x; den1 += w.y;
    }
#pragma unroll
    for (int off = 32; off >= 1; off >>= 1) {
        den0 += __shfl_xor(den0, off, 64);
        den1 += __shfl_xor(den1, off, 64);
    }
    int head = lane >> 5;
    float inv = 1.f / ((head ? den1 : den0) + GAT_EPS);
    // pass 2: weighted gather-accumulate (fp16 rows, fp32 accumulate)
    float accx = 0.f, accy = 0.f;
    int i = row;
    for (; i + 2 <= end; i += 2) {
        int s0 = csr_src[i], s1 = csr_src[i + 1];
        float2 w0 = w1v[i], w1e = w1v[i + 1];
        float2 ha = __half22float2(((const __half2*)(h1 + (size_t)s0 * 128))[lane]);
        float2 hb = __half22float2(((const __half2*)(h1 + (size_t)s1 * 128))[lane]);
        float wa = head ? w0.y : w0.x;
        float wb = head ? w1e.y : w1e.x;
        accx += wa * ha.x + wb * hb.x;
        accy += wa * ha.y + wb * hb.y;
    }
    if (i < end) {
        int s = csr_src[i];
        float2 w0 = w1v[i];
        float2 ha = __half22float2(((const __half2*)(h1 + (size_t)s * 128))[lane]);
        float wa = head ? w0.y : w0.x;
        accx += wa * ha.x; accy += wa * ha.y;
    }
    accx *= inv; accy *= inv;
    int c0 = lane * 2;
    float ox = accx + b1[c0], oy = accy + b1[c0 + 1];
    ox = (ox > 0.f) ? ox : expm1f(ox);   // ELU
    oy = (oy > 0.f) ? oy : expm1f(oy);
    rows[wv][c0] = ox;
    rows[wv][c0 + 1] = oy;
    __syncthreads();
    // fused gemm2: lane = j + 16*q; output j, k-range q*32..q*32+31
    int j = lane & 15, q = lane >> 4;
    const float* r = rows[wv];
    const float* wt = &w2t[j * 132];
    int k0 = q * 32;
    float acc2 = 0.f;
#pragma unroll
    for (int kk = 0; kk < 32; kk += 4) {
        float4 rv = *(const float4*)(r + k0 + kk);
        float4 w4 = *(const float4*)(wt + k0 + kk);
        acc2 += rv.x * w4.x + rv.y * w4.y + rv.z * w4.z + rv.w * w4.w;
    }
    acc2 += __shfl_xor(acc2, 16, 64);
    acc2 += __shfl_xor(acc2, 32, 64);
    if (lane < 16) {
        h2[(size_t)d * 16 + j] = acc2;
        float ps = acc2 * att_src2[j];
        float pd = acc2 * att_dst2[j];
#pragma unroll
        for (int off = 8; off >= 1; off >>= 1) {
            ps += __shfl_xor(ps, off, 64);
            pd += __shfl_xor(pd, off, 64);
        }
        if (lane == 0) { as2[d] = ps; ad2[d] = pd; }
    }
}

// ---------------- Layer 2 aggregation (weights on the fly) + bias + softmax ----------------
// 16 lanes per node.

__global__ __launch_bounds__(256) void k_agg2(
    const int* __restrict__ row_start, const int* __restrict__ csr_src,
    const float* __restrict__ h2, const float* __restrict__ as2,
    const float* __restrict__ ad2, const float* __restrict__ b2,
    float* __restrict__ out) {
    int gid = blockIdx.x * blockDim.x + threadIdx.x;
    int d = gid >> 4;
    int c = gid & 15;
    if (d >= N_NODES) return;
    int row = row_start[d], end = row_start[d + 1];
    float ad = ad2[d];
    float den = 0.f;
    for (int i = row + c; i < end; i += 16) {
        float e = as2[csr_src[i]] + ad;
        e = (e >= 0.f) ? e : NEG_SLOPE * e;
        den += expf(e);
    }
#pragma unroll
    for (int off = 8; off >= 1; off >>= 1) den += __shfl_xor(den, off, 16);
    float inv = 1.f / (den + GAT_EPS);
    float acc = 0.f;
    int i = row;
    for (; i + 2 <= end; i += 2) {
        int s0 = csr_src[i], s1 = csr_src[i + 1];
        float e0 = as2[s0] + ad; e0 = (e0 >= 0.f) ? e0 : NEG_SLOPE * e0;
        float e1 = as2[s1] + ad; e1 = (e1 >= 0.f) ? e1 : NEG_SLOPE * e1;
        acc += expf(e0) * h2[(size_t)s0 * 16 + c] + expf(e1) * h2[(size_t)s1 * 16 + c];
    }
    if (i < end) {
        int s = csr_src[i];
        float e = as2[s] + ad; e = (e >= 0.f) ? e : NEG_SLOPE * e;
        acc += expf(e) * h2[(size_t)s * 16 + c];
    }
    float v = acc * inv + b2[c];
    // softmax over the 16 channels
    float m = v;
#pragma unroll
    for (int off = 8; off >= 1; off >>= 1) m = fmaxf(m, __shfl_xor(m, off, 16));
    float ex = expf(v - m);
    float sum = ex;
#pragma unroll
    for (int off = 8; off >= 1; off >>= 1) sum += __shfl_xor(sum, off, 16);
    out[(size_t)d * 16 + c] = ex / sum;
}

// ---------------- launch ----------------

extern "C" void kernel_launch(void* const* d_in, const int* in_sizes, int n_in,
                              void* d_out, int out_size, void* d_ws, size_t ws_size,
                              hipStream_t stream) {
    const float* x        = (const float*)d_in[0];
    const float* W1       = (const float*)d_in[1];
    const float* att_src1 = (const float*)d_in[2];
    const float* att_dst1 = (const float*)d_in[3];
    const float* b1       = (const float*)d_in[4];
    const float* W2       = (const float*)d_in[5];
    const float* att_src2 = (const float*)d_in[6];
    const float* att_dst2 = (const float*)d_in[7];
    const float* b2       = (const float*)d_in[8];
    const int*   ei       = (const int*)d_in[9];   // [2, E]: src row then dst row

    char* p = (char*)d_ws;
    auto alloc = [&](size_t bytes) {
        char* r = p;
        p += (bytes + 255) & ~(size_t)255;
        return r;
    };
    __half* h1     = (__half*)alloc(sizeof(__half) * (size_t)N_NODES * 128);
    float* h2      = (float*)alloc(sizeof(float) * (size_t)N_NODES * 16);
    float* a_src   = (float*)alloc(sizeof(float) * N_NODES * 2);
    float* a_dst   = (float*)alloc(sizeof(float) * N_NODES * 2);
    float* as2     = (float*)alloc(sizeof(float) * N_NODES);
    float* ad2     = (float*)alloc(sizeof(float) * N_NODES);
    int* cnt       = (int*)alloc(sizeof(int) * N_NODES * 2);  // cnt + fill, adjacent
    int* fill      = cnt + N_NODES;
    int* row_start = (int*)alloc(sizeof(int) * (N_NODES + 1));
    int* csr_src   = (int*)alloc(sizeof(int) * N_EDGES);
    float* w1_csr  = (float*)alloc(sizeof(float) * (size_t)N_EDGES * 2);

    (void)hipMemsetAsync(cnt, 0, sizeof(int) * N_NODES * 2, stream);
    k_count<<<(N_EDGES + 255) / 256, 256, 0, stream>>>(ei, cnt);
    k_scan<<<1, 1024, 0, stream>>>(cnt, row_start);
    k_gemm1<<<(N_NODES + 31) / 32, 256, 0, stream>>>(x, W1, att_src1, att_dst1, h1, a_src, a_dst);
    k_scatter_w<<<(N_EDGES + 255) / 256, 256, 0, stream>>>(ei, row_start, fill, csr_src, a_src, a_dst, w1_csr);
    k_agg1f<<<N_NODES / 4, 256, 0, stream>>>(row_start, csr_src, h1, w1_csr, b1, W2, att_src2, att_dst2, h2, as2, ad2);
    k_agg2<<<(N_NODES * 16) / 256, 256, 0, stream>>>(row_start, csr_src, h2, as2, ad2, b2, (float*)d_out);
}